// Round 2
// baseline (14472.559 us; speedup 1.0000x reference)
//
#include <hip/hip_runtime.h>
#include <hip/hip_bf16.h>
#include <math.h>

#define SSH 4
#define SCALE 0.17677669529663687f  // 1/sqrt(32)

// ---------------- K1: LN1 + shift(-4,-4) + window partition ----------------
// one wave per token; lane covers ch, ch+64, ch+128
__global__ __launch_bounds__(256) void k_ln1(const float* __restrict__ x,
        const float* __restrict__ g, const float* __restrict__ bta,
        float* __restrict__ A){
    int lane = threadIdx.x & 63;
    int t = blockIdx.x*4 + (threadIdx.x>>6);      // 0..131071
    int win = t>>6, idx = t&63;
    int b = win>>8, rem = win&255, wh = rem>>4, wwi = rem&15;
    int r = idx>>3, c = idx&7;
    int sh = (wh*8 + r + SSH)&127, sw = (wwi*8 + c + SSH)&127;
    const float* src = x + (((size_t)(b*128 + sh))*128 + sw)*192;
    float v0 = src[lane], v1 = src[lane+64], v2 = src[lane+128];
    float s = v0+v1+v2, ss = v0*v0+v1*v1+v2*v2;
    #pragma unroll
    for (int m=32;m;m>>=1){ s += __shfl_xor(s,m); ss += __shfl_xor(ss,m); }
    float mean = s*(1.f/192.f);
    float rstd = rsqrtf(ss*(1.f/192.f) - mean*mean + 1e-5f);
    float* dst = A + (size_t)t*192;
    dst[lane]     = (v0-mean)*rstd*g[lane]     + bta[lane];
    dst[lane+64]  = (v1-mean)*rstd*g[lane+64]  + bta[lane+64];
    dst[lane+128] = (v2-mean)*rstd*g[lane+128] + bta[lane+128];
}

// ---------------- K2: spatial window attention (writes Bbuf = d_out) --------
__global__ __launch_bounds__(256) void k_spatial(const float* __restrict__ A,
        const float* __restrict__ qkv_w, const float* __restrict__ qkv_b,
        const float* __restrict__ relt, const float* __restrict__ mask,
        float* __restrict__ Bbuf){
    __shared__ float xw[64*196];
    __shared__ float qs[64*33], ks[64*33], vs[64*33];
    __shared__ float Wt[192*32];
    __shared__ float S[64*66];
    int tid = threadIdx.x;
    int win = blockIdx.x;
    int widx = win & 255;
    const float* src = A + (size_t)win*12288;
    #pragma unroll
    for (int i=0;i<12;i++){
        int e = tid + i*256;              // 3072 float4
        int row = e/48, q4 = e - row*48;
        float4 v = *reinterpret_cast<const float4*>(src + row*192 + q4*4);
        *reinterpret_cast<float4*>(&xw[row*196 + q4*4]) = v;
    }
    int n_o = tid>>2;
    int d0  = (tid&3)*8;
    for (int h=0; h<6; h++){
        for (int m=0; m<3; m++){
            __syncthreads();
            #pragma unroll
            for (int i=0;i<24;i++){
                int e = tid + i*256;      // 6144
                int ch = e>>5, d = e&31;
                Wt[e] = qkv_w[ch*576 + m*192 + h*32 + d];
            }
            __syncthreads();
            float acc[8];
            #pragma unroll
            for (int j=0;j<8;j++) acc[j]=0.f;
            for (int ch=0; ch<192; ch++){
                float a = xw[n_o*196 + ch];
                #pragma unroll
                for (int j=0;j<8;j++) acc[j] += a * Wt[ch*32 + d0 + j];
            }
            float* dstq = (m==0)?qs:((m==1)?ks:vs);
            #pragma unroll
            for (int j=0;j<8;j++)
                dstq[n_o*33 + d0 + j] = acc[j] + qkv_b[m*192 + h*32 + d0 + j];
        }
        __syncthreads();
        float qreg[32];
        #pragma unroll
        for (int d=0; d<32; d++) qreg[d] = qs[n_o*33 + d];
        float sc[16];
        int c0 = (tid&3)*16;
        #pragma unroll
        for (int j=0;j<16;j++){
            int col = c0 + j;
            float dot = 0.f;
            #pragma unroll
            for (int d=0; d<32; d++) dot += qreg[d] * ks[col*33 + d];
            int dr = (n_o>>3) - (col>>3) + 7;
            int dc = (n_o&7)  - (col&7)  + 7;
            float bias = relt[(dr*15 + dc)*6 + h];
            float mk   = mask[((widx*64 + n_o)<<6) + col];
            sc[j] = dot*SCALE + bias + mk;
        }
        float mx = sc[0];
        #pragma unroll
        for (int j=1;j<16;j++) mx = fmaxf(mx, sc[j]);
        mx = fmaxf(mx, __shfl_xor(mx,1));
        mx = fmaxf(mx, __shfl_xor(mx,2));
        float sum = 0.f;
        #pragma unroll
        for (int j=0;j<16;j++){ sc[j] = __expf(sc[j]-mx); sum += sc[j]; }
        sum += __shfl_xor(sum,1);
        sum += __shfl_xor(sum,2);
        float inv = 1.f/sum;
        #pragma unroll
        for (int j=0;j<16;j++) S[n_o*66 + c0 + j] = sc[j]*inv;
        __syncthreads();
        float oacc[8];
        #pragma unroll
        for (int j=0;j<8;j++) oacc[j]=0.f;
        for (int mcol=0; mcol<64; mcol++){
            float p = S[n_o*66 + mcol];
            #pragma unroll
            for (int j=0;j<8;j++) oacc[j] += p * vs[mcol*33 + d0 + j];
        }
        float* outp = Bbuf + ((size_t)win*64 + n_o)*192 + h*32 + d0;
        #pragma unroll
        for (int j=0;j<8;j++) outp[j] = oacc[j];
    }
}

// ------- K3: fused Fourier branch per window: rfft2 -> attn(6 heads) -> irfft2, += into Bbuf
__global__ __launch_bounds__(256) void k_fattn(const float* __restrict__ A,
        const float* __restrict__ qkv_w, const float* __restrict__ qkv_b,
        float* __restrict__ Bbuf){
    __shared__ float smem[33584];         // 134,336 B arena
    __shared__ float cs[8], sn[8];
    float* xfre = smem;                   // 7680 (40 uv x 192 ch)
    float* xfim = smem + 7680;            // 7680
    float* U    = smem + 15360;           // union region, 18224 floats
    float* xw   = U;                      // 12288 (FFT build only)
    float* qf0  = U;                      // 40x33
    float* qf1  = U + 1320;
    float* kf0  = U + 2640;
    float* kf1  = U + 3960;
    float* vf0  = U + 5280;
    float* vf1  = U + 6600;
    float* Smat = U + 7920;               // 1600
    float* rr   = U + 9520;               // 1280
    float* ri   = U + 10800;              // 1280
    float* Wt   = U + 12080;              // 6144 -> 18224
    int tid = threadIdx.x;
    int win = blockIdx.x;
    if (tid < 8){
        float ang = (float)tid * 0.78539816339744831f;  // 2*pi*k/8
        cs[tid] = cosf(ang); sn[tid] = sinf(ang);
    }
    const float* src = A + (size_t)win*12288;
    #pragma unroll
    for (int i=0;i<12;i++){
        int e = tid + i*256;
        *reinterpret_cast<float4*>(&xw[e*4]) =
            *reinterpret_cast<const float4*>(src + e*4);
    }
    __syncthreads();
    // rfft2 ortho: G[u,v,ch] = (1/8) sum_{r,c} x[r,c,ch] e^{-2pi i(ur+vc)/8}
    for (int i=0;i<30;i++){
        int o = tid + i*256;              // 7680
        int uv = o/192, ch = o - uv*192;
        int u = uv/5, vv = uv - u*5;
        float re=0.f, im=0.f;
        for (int r=0;r<8;r++){
            int ur = (u*r)&7;
            #pragma unroll
            for (int c=0;c<8;c++){
                int k = (ur + vv*c)&7;
                float a = xw[((r<<3)+c)*192 + ch];
                re += a*cs[k];
                im -= a*sn[k];
            }
        }
        xfre[o] = re*0.125f;
        xfim[o] = im*0.125f;
    }
    for (int h=0; h<6; h++){
        for (int m=0; m<3; m++){
            __syncthreads();              // protects xw/xf (h=0,m=0) and prior-stage readers
            #pragma unroll
            for (int i=0;i<24;i++){
                int e = tid + i*256;      // 6144
                int ch = e>>5, d = e&31;
                Wt[e] = qkv_w[ch*576 + m*192 + h*32 + d];
            }
            __syncthreads();
            float* o0 = (m==0)?qf0:((m==1)?kf0:vf0);
            float* o1 = (m==0)?qf1:((m==1)?kf1:vf1);
            #pragma unroll
            for (int i=0;i<5;i++){
                int o = tid + i*256;      // 1280 = 40n x 32d
                int n = o>>5, d = o&31;
                float bias = qkv_b[m*192 + h*32 + d];
                float ar = bias, ai = bias;   // bias on both real & imag parts
                for (int ch=0; ch<192; ch++){
                    float w = Wt[ch*32 + d];
                    ar += xfre[n*192+ch]*w;
                    ai += xfim[n*192+ch]*w;
                }
                o0[n*33+d] = ar;
                o1[n*33+d] = ai;
            }
        }
        __syncthreads();
        // scores: |q.k| * scale (no conj, plain complex product)
        for (int o = tid; o < 1600; o += 256){
            int n = o/40, mc = o - n*40;
            float sre=0.f, sim=0.f;
            #pragma unroll
            for (int d=0; d<32; d++){
                float qr = qf0[n*33+d], qi = qf1[n*33+d];
                float kr = kf0[mc*33+d], ki = kf1[mc*33+d];
                sre += qr*kr - qi*ki;
                sim += qr*ki + qi*kr;
            }
            Smat[o] = SCALE * sqrtf(sre*sre + sim*sim);
        }
        __syncthreads();
        if (tid < 160){
            int row = tid>>2, part = tid&3;
            int e0 = part*10;
            float mx = -1e30f;
            #pragma unroll
            for (int j=0;j<10;j++) mx = fmaxf(mx, Smat[row*40 + e0 + j]);
            mx = fmaxf(mx, __shfl_xor(mx,1));
            mx = fmaxf(mx, __shfl_xor(mx,2));
            float ex[10]; float sum=0.f;
            #pragma unroll
            for (int j=0;j<10;j++){ ex[j] = __expf(Smat[row*40+e0+j]-mx); sum += ex[j]; }
            sum += __shfl_xor(sum,1);
            sum += __shfl_xor(sum,2);
            float inv = 1.f/sum;
            #pragma unroll
            for (int j=0;j<10;j++) Smat[row*40+e0+j] = ex[j]*inv;
        }
        __syncthreads();
        // res = P @ Vf (P real)
        #pragma unroll
        for (int i=0;i<5;i++){
            int o = tid + i*256;
            int n = o>>5, d = o&31;
            float ar=0.f, ai=0.f;
            for (int mc=0; mc<40; mc++){
                float s = Smat[n*40+mc];
                ar += s*vf0[mc*33+d];
                ai += s*vf1[mc*33+d];
            }
            rr[o]=ar; ri[o]=ai;
        }
        __syncthreads();
        // irfft2 ortho (general non-Hermitian input, numpy semantics):
        // x[r,c] = (1/8) sum_u sum_{v=0..4} w_v Re(G[u,v] e^{+2pi i(ur+vc)/8}),
        // w_v = 2 for v in {1,2,3}, else 1
        #pragma unroll
        for (int i=0;i<8;i++){
            int o = tid + i*256;          // 2048 = 64 pix x 32 d
            int pix = o>>5, d = o&31;
            int r = pix>>3, c = pix&7;
            float acc = 0.f;
            for (int u=0;u<8;u++){
                int ur = (u*r)&7;
                #pragma unroll
                for (int vv=0; vv<5; vv++){
                    int k = (ur + vv*c)&7;
                    float wv = (vv==0 || vv==4) ? 1.f : 2.f;
                    int idx = (u*5+vv)*32 + d;
                    acc += wv*(rr[idx]*cs[k] - ri[idx]*sn[k]);
                }
            }
            Bbuf[((size_t)win*64 + pix)*192 + h*32 + d] += acc*0.125f;
        }
    }
}

// ---------------- K4: proj + window reverse + unshift + residual -> X1 (=A) --
__global__ __launch_bounds__(256) void k_proj(const float* __restrict__ Bbuf,
        const float* __restrict__ x, const float* __restrict__ proj_w,
        const float* __restrict__ proj_b, float* __restrict__ X1){
    __shared__ float tile[64*196];
    __shared__ float Wp[32*192];
    int tid = threadIdx.x;
    int win = blockIdx.x;
    const float* src = Bbuf + (size_t)win*12288;
    #pragma unroll
    for (int i=0;i<12;i++){
        int e = tid + i*256;
        int row = e/48, q4 = e - row*48;
        float4 v = *reinterpret_cast<const float4*>(src + row*192 + q4*4);
        *reinterpret_cast<float4*>(&tile[row*196 + q4*4]) = v;
    }
    int rg = tid & 15, cg = tid >> 4;
    float acc[4][12];
    #pragma unroll
    for (int a=0;a<4;a++)
        #pragma unroll
        for (int c=0;c<12;c++) acc[a][c]=0.f;
    for (int kk=0; kk<192; kk+=32){
        __syncthreads();
        #pragma unroll
        for (int i=0;i<24;i++){
            int e = tid + i*256;          // 6144
            int k = e/192, ch = e - k*192;
            Wp[e] = proj_w[(kk+k)*192 + ch];
        }
        __syncthreads();
        for (int k=0;k<32;k++){
            float av[4];
            #pragma unroll
            for (int a=0;a<4;a++) av[a] = tile[(rg+16*a)*196 + kk + k];
            #pragma unroll
            for (int c=0;c<12;c++){
                float w = Wp[k*192 + cg*12 + c];
                #pragma unroll
                for (int a=0;a<4;a++) acc[a][c] += av[a]*w;
            }
        }
    }
    int b = win>>8, rem = win&255, wh = rem>>4, wwi = rem&15;
    #pragma unroll
    for (int a=0;a<4;a++){
        int t = rg + 16*a;
        int p = wh*8 + (t>>3), q = wwi*8 + (t&7);
        int hh = (p+SSH)&127, w2 = (q+SSH)&127;
        size_t pixb = (((size_t)b*128 + hh)*128 + w2)*192;
        #pragma unroll
        for (int c=0;c<12;c++){
            int ch = cg*12 + c;
            X1[pixb + ch] = acc[a][c] + proj_b[ch] + x[pixb + ch];
        }
    }
}

// ---------------- K5: LN2 + fc1 + exact GELU + fc2 + residual -> out ---------
__global__ __launch_bounds__(256) void k_mlp(const float* __restrict__ X1,
        const float* __restrict__ g2, const float* __restrict__ b2v,
        const float* __restrict__ fc1w, const float* __restrict__ fc1b,
        const float* __restrict__ fc2w, const float* __restrict__ fc2b,
        float* __restrict__ out){
    __shared__ float xln[64*196];
    __shared__ float Wbuf[12288];
    __shared__ float hch[64*68];
    int tid = threadIdx.x;
    size_t base = (size_t)blockIdx.x*64;
    {
        int tok = tid>>2, part = tid&3;
        const float* srcp = X1 + (base + tok)*192 + part*48;
        float v[48];
        #pragma unroll
        for (int i=0;i<12;i++){
            float4 t4 = *reinterpret_cast<const float4*>(srcp + i*4);
            v[i*4]=t4.x; v[i*4+1]=t4.y; v[i*4+2]=t4.z; v[i*4+3]=t4.w;
        }
        float s=0.f, ss=0.f;
        #pragma unroll
        for (int i=0;i<48;i++){ s+=v[i]; ss+=v[i]*v[i]; }
        s  += __shfl_xor(s,1);  s  += __shfl_xor(s,2);
        ss += __shfl_xor(ss,1); ss += __shfl_xor(ss,2);
        float mean = s*(1.f/192.f);
        float rstd = rsqrtf(ss*(1.f/192.f) - mean*mean + 1e-5f);
        #pragma unroll
        for (int i=0;i<48;i++){
            int ch = part*48 + i;
            xln[tok*196 + ch] = (v[i]-mean)*rstd*g2[ch] + b2v[ch];
        }
    }
    int rg = tid&15, cg = tid>>4;
    float acc[4][12];
    #pragma unroll
    for (int a=0;a<4;a++)
        #pragma unroll
        for (int c=0;c<12;c++) acc[a][c]=0.f;
    for (int cc=0; cc<12; cc++){
        __syncthreads();
        #pragma unroll
        for (int i=0;i<48;i++){
            int e = tid + i*256;          // 12288: W1 chunk [192][64]
            int ch = e>>6, j = e&63;
            Wbuf[e] = fc1w[ch*768 + cc*64 + j];
        }
        __syncthreads();
        float hv[4][4];
        #pragma unroll
        for (int a=0;a<4;a++)
            #pragma unroll
            for (int jb=0;jb<4;jb++) hv[a][jb] = fc1b[cc*64 + cg*4 + jb];
        for (int ch=0; ch<192; ch++){
            float av[4];
            #pragma unroll
            for (int a=0;a<4;a++) av[a] = xln[(rg+16*a)*196 + ch];
            #pragma unroll
            for (int jb=0;jb<4;jb++){
                float w = Wbuf[ch*64 + cg*4 + jb];
                #pragma unroll
                for (int a=0;a<4;a++) hv[a][jb] += av[a]*w;
            }
        }
        #pragma unroll
        for (int a=0;a<4;a++)
            #pragma unroll
            for (int jb=0;jb<4;jb++){
                float xv = hv[a][jb];
                hch[(rg+16*a)*68 + cg*4 + jb] =
                    0.5f*xv*(1.f + erff(xv*0.70710678118654752f));
            }
        __syncthreads();
        #pragma unroll
        for (int i=0;i<48;i++){
            int e = tid + i*256;          // W2 chunk [64][192]
            int j = e/192, ch = e - j*192;
            Wbuf[e] = fc2w[(cc*64 + j)*192 + ch];
        }
        __syncthreads();
        for (int j=0;j<64;j++){
            float hvv[4];
            #pragma unroll
            for (int a=0;a<4;a++) hvv[a] = hch[(rg+16*a)*68 + j];
            #pragma unroll
            for (int c=0;c<12;c++){
                float w = Wbuf[j*192 + cg*12 + c];
                #pragma unroll
                for (int a=0;a<4;a++) acc[a][c] += hvv[a]*w;
            }
        }
    }
    #pragma unroll
    for (int a=0;a<4;a++){
        size_t t = base + rg + 16*a;
        #pragma unroll
        for (int c=0;c<12;c++){
            int ch = cg*12 + c;
            out[t*192 + ch] = acc[a][c] + fc2b[ch] + X1[t*192 + ch];
        }
    }
}

extern "C" void kernel_launch(void* const* d_in, const int* in_sizes, int n_in,
                              void* d_out, int out_size, void* d_ws, size_t ws_size,
                              hipStream_t stream) {
    const float* x     = (const float*)d_in[0];
    const float* mask  = (const float*)d_in[1];
    const float* n1g   = (const float*)d_in[2];
    const float* n1b   = (const float*)d_in[3];
    const float* qkvw  = (const float*)d_in[4];
    const float* qkvb  = (const float*)d_in[5];
    const float* relt  = (const float*)d_in[6];
    const float* projw = (const float*)d_in[7];
    const float* projb = (const float*)d_in[8];
    const float* n2g   = (const float*)d_in[9];
    const float* n2b   = (const float*)d_in[10];
    const float* fc1w  = (const float*)d_in[11];
    const float* fc1b  = (const float*)d_in[12];
    const float* fc2w  = (const float*)d_in[13];
    const float* fc2b  = (const float*)d_in[14];
    float* out = (float*)d_out;

    float* A = (float*)d_ws;   // 25,165,824 floats = 100.66 MB (LN1 windows, later X1)

    k_ln1    <<<32768, 256, 0, stream>>>(x, n1g, n1b, A);
    k_spatial<<<2048,  256, 0, stream>>>(A, qkvw, qkvb, relt, mask, out);
    k_fattn  <<<2048,  256, 0, stream>>>(A, qkvw, qkvb, out);
    k_proj   <<<2048,  256, 0, stream>>>(out, x, projw, projb, A);
    k_mlp    <<<2048,  256, 0, stream>>>(A, n2g, n2b, fc1w, fc1b, fc2w, fc2b, out);
}

// Round 3
// 2977.249 us; speedup vs baseline: 4.8611x; 4.8611x over previous
//
#include <hip/hip_runtime.h>
#include <hip/hip_bf16.h>
#include <math.h>

typedef __hip_bfloat16 bf16;

#define SSH 4
#define SCALE 0.17677669529663687f  // 1/sqrt(32)

// ---------------- K1: fused LN1 + shift + window partition + qkv GEMM -> S (bf16, with bias)
// grid = 3 chunks * 2048 windows; block 256. S[t][cc], cc = m*192 + h*32 + d
__global__ __launch_bounds__(256,3) void k_qkv(const float* __restrict__ x,
        const float* __restrict__ n1g, const float* __restrict__ n1b,
        const float* __restrict__ qkv_w, const float* __restrict__ qkv_b,
        bf16* __restrict__ S){
    __shared__ bf16 xw[64*200];
    __shared__ __align__(16) float Wt[32*192];
    int tid = threadIdx.x;
    int win = blockIdx.x & 2047;
    int chunk = blockIdx.x >> 11;
    int b = win>>8, rem = win&255, wh = rem>>4, wwi = rem&15;
    {   // LN1 on shifted window tokens (4 threads per token)
        int tok = tid>>2, part = tid&3;
        int r = tok>>3, c = tok&7;
        int sh = (wh*8 + r + SSH)&127, sw = (wwi*8 + c + SSH)&127;
        const float* srcp = x + (((size_t)(b*128+sh))*128 + sw)*192 + part*48;
        float v[48];
        #pragma unroll
        for (int i=0;i<12;i++){
            float4 t4 = *reinterpret_cast<const float4*>(srcp + i*4);
            v[i*4]=t4.x; v[i*4+1]=t4.y; v[i*4+2]=t4.z; v[i*4+3]=t4.w;
        }
        float s=0.f, ss=0.f;
        #pragma unroll
        for (int i=0;i<48;i++){ s+=v[i]; ss+=v[i]*v[i]; }
        s  += __shfl_xor(s,1);  s  += __shfl_xor(s,2);
        ss += __shfl_xor(ss,1); ss += __shfl_xor(ss,2);
        float mean = s*(1.f/192.f);
        float rstd = rsqrtf(ss*(1.f/192.f) - mean*mean + 1e-5f);
        #pragma unroll
        for (int i=0;i<48;i++){
            int ch = part*48 + i;
            xw[tok*200 + ch] = __float2bfloat16((v[i]-mean)*rstd*n1g[ch] + n1b[ch]);
        }
    }
    int rg = tid&15, cg = tid>>4;
    float acc[4][12];
    #pragma unroll
    for (int a=0;a<4;a++)
        #pragma unroll
        for (int c=0;c<12;c++) acc[a][c]=0.f;
    for (int kk=0; kk<192; kk+=32){
        __syncthreads();
        #pragma unroll
        for (int i=0;i<24;i++){
            int e = tid + i*256;           // 6144
            int k = e/192, ch = e - k*192;
            Wt[e] = qkv_w[(size_t)(kk+k)*576 + chunk*192 + ch];
        }
        __syncthreads();
        for (int k=0;k<32;k++){
            float av[4];
            #pragma unroll
            for (int a=0;a<4;a++) av[a] = __bfloat162float(xw[(rg+16*a)*200 + kk + k]);
            const float4* wp = reinterpret_cast<const float4*>(&Wt[k*192 + cg*12]);
            float4 w0 = wp[0], w1 = wp[1], w2 = wp[2];
            float w[12] = {w0.x,w0.y,w0.z,w0.w, w1.x,w1.y,w1.z,w1.w, w2.x,w2.y,w2.z,w2.w};
            #pragma unroll
            for (int c=0;c<12;c++)
                #pragma unroll
                for (int a=0;a<4;a++) acc[a][c] += av[a]*w[c];
        }
    }
    #pragma unroll
    for (int a=0;a<4;a++){
        size_t row = (size_t)win*64 + rg + 16*a;
        #pragma unroll
        for (int c=0;c<12;c++){
            int col = chunk*192 + cg*12 + c;
            S[row*576 + col] = __float2bfloat16(acc[a][c] + qkv_b[col]);
        }
    }
}

// ---------------- K2: spatial window attention from S -> Bbuf (d_out) --------
__global__ __launch_bounds__(256,3) void k_spatial(const bf16* __restrict__ S,
        const float* __restrict__ relt, const float* __restrict__ mask,
        float* __restrict__ Bbuf){
    __shared__ __align__(16) float qs[64*36], ks[64*36], vs[64*36];
    __shared__ float Sc[64*66];
    int tid = threadIdx.x;
    int win = blockIdx.x;
    int widx = win & 255;
    int n_o = tid>>2;
    int d0  = (tid&3)*8;
    int c0  = (tid&3)*16;
    for (int h=0; h<6; h++){
        __syncthreads();
        #pragma unroll
        for (int i=0;i<24;i++){
            int e = tid + i*256;           // 6144 = 3m x 64row x 32d
            int m = e>>11, rem2 = e&2047, row = rem2>>5, d = rem2&31;
            float v = __bfloat162float(S[((size_t)win*64+row)*576 + m*192 + h*32 + d]);
            float* dst = (m==0)?qs:((m==1)?ks:vs);
            dst[row*36+d] = v;
        }
        __syncthreads();
        float qreg[32];
        #pragma unroll
        for (int i=0;i<8;i++){
            float4 q4 = *reinterpret_cast<const float4*>(&qs[n_o*36 + i*4]);
            qreg[i*4]=q4.x; qreg[i*4+1]=q4.y; qreg[i*4+2]=q4.z; qreg[i*4+3]=q4.w;
        }
        float sc[16];
        #pragma unroll
        for (int j=0;j<16;j++){
            int col = c0 + j;
            float dot = 0.f;
            #pragma unroll
            for (int i=0;i<8;i++){
                float4 k4 = *reinterpret_cast<const float4*>(&ks[col*36 + i*4]);
                dot += qreg[i*4]*k4.x + qreg[i*4+1]*k4.y + qreg[i*4+2]*k4.z + qreg[i*4+3]*k4.w;
            }
            int dr = (n_o>>3) - (col>>3) + 7;
            int dc = (n_o&7)  - (col&7)  + 7;
            float bias = relt[(dr*15 + dc)*6 + h];
            float mk   = mask[((widx*64 + n_o)<<6) + col];
            sc[j] = dot*SCALE + bias + mk;
        }
        float mx = sc[0];
        #pragma unroll
        for (int j=1;j<16;j++) mx = fmaxf(mx, sc[j]);
        mx = fmaxf(mx, __shfl_xor(mx,1));
        mx = fmaxf(mx, __shfl_xor(mx,2));
        float sum = 0.f;
        #pragma unroll
        for (int j=0;j<16;j++){ sc[j] = __expf(sc[j]-mx); sum += sc[j]; }
        sum += __shfl_xor(sum,1);
        sum += __shfl_xor(sum,2);
        float inv = 1.f/sum;
        #pragma unroll
        for (int j=0;j<16;j++) Sc[n_o*66 + c0 + j] = sc[j]*inv;
        __syncthreads();
        float oacc[8];
        #pragma unroll
        for (int j=0;j<8;j++) oacc[j]=0.f;
        for (int mcol=0; mcol<64; mcol++){
            float p = Sc[n_o*66 + mcol];
            float4 v0 = *reinterpret_cast<const float4*>(&vs[mcol*36 + d0]);
            float4 v1 = *reinterpret_cast<const float4*>(&vs[mcol*36 + d0 + 4]);
            oacc[0]+=p*v0.x; oacc[1]+=p*v0.y; oacc[2]+=p*v0.z; oacc[3]+=p*v0.w;
            oacc[4]+=p*v1.x; oacc[5]+=p*v1.y; oacc[6]+=p*v1.z; oacc[7]+=p*v1.w;
        }
        float* outp = Bbuf + ((size_t)win*64 + n_o)*192 + h*32 + d0;
        *reinterpret_cast<float4*>(outp)   = make_float4(oacc[0],oacc[1],oacc[2],oacc[3]);
        *reinterpret_cast<float4*>(outp+4) = make_float4(oacc[4],oacc[5],oacc[6],oacc[7]);
    }
}

// ------- K3: Fourier branch per (window, head): FFT(S_h) -> attn -> iFFT, += into Bbuf
__global__ __launch_bounds__(256,3) void k_fattn(const bf16* __restrict__ S,
        const float* __restrict__ qkv_b, float* __restrict__ Bbuf){
    __shared__ __align__(16) float2 qf[40*33], kf[40*33], vf[40*33]; // 31,680 B
    __shared__ __align__(16) float U[5248];                         // 20,992 B union
    __shared__ float csl[8], snl[8];
    int tid = threadIdx.x;
    int win = blockIdx.x / 6;
    int h   = blockIdx.x - win*6;
    if (tid < 8){
        float ang = (float)tid * 0.78539816339744831f;  // 2*pi*t/8
        csl[tid] = cosf(ang); snl[tid] = sinf(ang);
    }
    int d = tid&31, g = tid>>5;    // d: head-dim lane, g: 0..7 group
    __syncthreads();
    // stage-A twiddles: w_r = e^{-2pi i g r/8}
    float wrr[8], wri[8];
    {
        float cu = csl[g], su = snl[g];
        float wr = 1.f, wi = 0.f;
        #pragma unroll
        for (int r=0;r<8;r++){
            wrr[r]=wr; wri[r]=wi;
            float nr = wr*cu + wi*su, ni = wi*cu - wr*su;
            wr=nr; wi=ni;
        }
    }
    bf16* Sh = (bf16*)U;                                   // [64][36] bf16, 4608 B
    float2* Tc = reinterpret_cast<float2*>(U + 1152);      // [8u][8c][32d], 16384 B
    for (int m=0;m<3;m++){
        __syncthreads();
        #pragma unroll
        for (int i=0;i<8;i++){
            int e = tid + i*256;           // 2048
            int p = e>>5, dd = e&31;
            Sh[p*36+dd] = S[((size_t)win*64+p)*576 + m*192 + h*32 + dd];
        }
        __syncthreads();
        // stage A (row FFT): T[u=g][c][d] = sum_r Sh[r*8+c][d] * e^{-2pi i g r/8}
        #pragma unroll
        for (int c=0;c<8;c++){
            float tre=0.f, tim=0.f;
            #pragma unroll
            for (int r=0;r<8;r++){
                float s = __bfloat162float(Sh[(r*8+c)*36 + d]);
                tre += s*wrr[r]; tim += s*wri[r];
            }
            Tc[(g*8+c)*32 + d] = make_float2(tre, tim);
        }
        __syncthreads();
        // stage B (col FFT): n = g*5+v; includes ortho 1/8 and exact bias fix
        float bias = qkv_b[m*192 + h*32 + d];
        float2* dstf = (m==0)?qf:((m==1)?kf:vf);
        #pragma unroll
        for (int v=0;v<5;v++){
            float cv = csl[v], sv = snl[v];
            float wr=1.f, wi=0.f, ar=0.f, ai=0.f;
            #pragma unroll
            for (int c=0;c<8;c++){
                float2 t = Tc[(g*8+c)*32 + d];
                ar += t.x*wr - t.y*wi;
                ai += t.x*wi + t.y*wr;
                float nr = wr*cv + wi*sv, ni = wi*cv - wr*sv;  // *= e^{-2pi i v/8}
                wr=nr; wi=ni;
            }
            int n = g*5+v;
            // S has bias: F.S = F.S_nb + 8b at n==0 (re). want F.S_nb + b(1+i)
            float cre = ar*0.125f + ((n==0)? -7.f*bias : bias);
            float cim = ai*0.125f + bias;
            dstf[n*33+d] = make_float2(cre, cim);
        }
    }
    __syncthreads();
    float* Smat = U + 2560;        // 1600 floats @ byte 10240
    for (int o=tid; o<1600; o+=256){
        unsigned n = (unsigned)o/40u; int mc = o - (int)n*40;
        float sre=0.f, sim=0.f;
        #pragma unroll
        for (int dd=0; dd<32; dd++){
            float2 q = qf[n*33+dd];
            float2 k = kf[mc*33+dd];
            sre += q.x*k.x - q.y*k.y;
            sim += q.x*k.y + q.y*k.x;
        }
        Smat[o] = SCALE * sqrtf(sre*sre + sim*sim);
    }
    __syncthreads();
    if (tid < 160){
        int row = tid>>2, part = tid&3, e0 = part*10;
        float mx = -1e30f;
        #pragma unroll
        for (int j=0;j<10;j++) mx = fmaxf(mx, Smat[row*40 + e0 + j]);
        mx = fmaxf(mx, __shfl_xor(mx,1));
        mx = fmaxf(mx, __shfl_xor(mx,2));
        float ex[10]; float sum=0.f;
        #pragma unroll
        for (int j=0;j<10;j++){ ex[j] = __expf(Smat[row*40+e0+j]-mx); sum += ex[j]; }
        sum += __shfl_xor(sum,1);
        sum += __shfl_xor(sum,2);
        float inv = 1.f/sum;
        #pragma unroll
        for (int j=0;j<10;j++) Smat[row*40+e0+j] = ex[j]*inv;
    }
    __syncthreads();
    // PV (P real): rv[n][d] = sum_mc P[n,mc] * vf[mc][d]
    float2* rv = reinterpret_cast<float2*>(U);   // [40][32] @ byte 0
    {
        float ar[5], ai[5];
        #pragma unroll
        for (int j=0;j<5;j++){ ar[j]=0.f; ai[j]=0.f; }
        for (int mc=0; mc<40; mc++){
            float2 v = vf[mc*33+d];
            #pragma unroll
            for (int j=0;j<5;j++){
                float s = Smat[(g*5+j)*40 + mc];
                ar[j] += s*v.x; ai[j] += s*v.y;
            }
        }
        #pragma unroll
        for (int j=0;j<5;j++) rv[(g*5+j)*32 + d] = make_float2(ar[j], ai[j]);
    }
    // iFFT (ortho, numpy irfftn semantics), two-stage, split over u-halves
    float2* Tc2 = reinterpret_cast<float2*>(U + 2560);  // 8192 B over dead Smat
    float xacc[8];
    #pragma unroll
    for (int c=0;c<8;c++) xacc[c]=0.f;
    float wur = 1.f, wui = 0.f;                 // e^{+2pi i u g/8}, advanced over u
    float crr = csl[g], srr = snl[g];
    for (int half=0; half<2; half++){
        __syncthreads();
        {   // stage 1: Tc2[u][c][d] = sum_v wv * G[u,v,d] * e^{+2pi i v c/8}
            int u = half*4 + (g&3);
            int cbase = (g>>2)*4;
            #pragma unroll
            for (int cc=0; cc<4; cc++){
                int c = cbase + cc;
                float stepr = csl[c], stepi = snl[c];
                float wr=1.f, wi=0.f, ar=0.f, ai=0.f;
                #pragma unroll
                for (int v=0; v<5; v++){
                    float2 Gv = rv[(u*5+v)*32 + d];
                    float wv = (v>=1 && v<=3)? 2.f : 1.f;
                    float gx = Gv.x*wv, gy = Gv.y*wv;
                    ar += gx*wr - gy*wi;
                    ai += gx*wi + gy*wr;
                    float nr = wr*stepr - wi*stepi, ni = wr*stepi + wi*stepr;
                    wr=nr; wi=ni;
                }
                Tc2[((u&3)*8 + c)*32 + d] = make_float2(ar, ai);
            }
        }
        __syncthreads();
        {   // stage 2: x[r=g][c][d] += Re{ Tc2[u][c][d] * e^{+2pi i u g/8} }
            #pragma unroll
            for (int uu=0; uu<4; uu++){
                float wrc = wur, wic = wui;
                #pragma unroll
                for (int c=0;c<8;c++){
                    float2 t = Tc2[(uu*8 + c)*32 + d];
                    xacc[c] += t.x*wrc - t.y*wic;
                }
                float nr = wur*crr - wui*srr, ni = wur*srr + wui*crr;
                wur=nr; wui=ni;
            }
        }
    }
    #pragma unroll
    for (int c=0;c<8;c++){
        size_t idx = ((size_t)win*64 + g*8 + c)*192 + h*32 + d;
        Bbuf[idx] += 0.125f*xacc[c];
    }
}

// ---------------- K4: proj + window reverse + unshift + residual -> X1 -------
__global__ __launch_bounds__(256) void k_proj(const float* __restrict__ Bbuf,
        const float* __restrict__ x, const float* __restrict__ proj_w,
        const float* __restrict__ proj_b, float* __restrict__ X1){
    __shared__ __align__(16) float tile[64*196];
    __shared__ __align__(16) float Wp[32*192];
    int tid = threadIdx.x;
    int win = blockIdx.x;
    const float* src = Bbuf + (size_t)win*12288;
    #pragma unroll
    for (int i=0;i<12;i++){
        int e = tid + i*256;
        int row = e/48, q4 = e - row*48;
        float4 v = *reinterpret_cast<const float4*>(src + row*192 + q4*4);
        *reinterpret_cast<float4*>(&tile[row*196 + q4*4]) = v;
    }
    int rg = tid & 15, cg = tid >> 4;
    float acc[4][12];
    #pragma unroll
    for (int a=0;a<4;a++)
        #pragma unroll
        for (int c=0;c<12;c++) acc[a][c]=0.f;
    for (int kk=0; kk<192; kk+=32){
        __syncthreads();
        #pragma unroll
        for (int i=0;i<24;i++){
            int e = tid + i*256;
            int k = e/192, ch = e - k*192;
            Wp[e] = proj_w[(kk+k)*192 + ch];
        }
        __syncthreads();
        for (int k=0;k<32;k++){
            float av[4];
            #pragma unroll
            for (int a=0;a<4;a++) av[a] = tile[(rg+16*a)*196 + kk + k];
            const float4* wp = reinterpret_cast<const float4*>(&Wp[k*192 + cg*12]);
            float4 w0 = wp[0], w1 = wp[1], w2 = wp[2];
            float w[12] = {w0.x,w0.y,w0.z,w0.w, w1.x,w1.y,w1.z,w1.w, w2.x,w2.y,w2.z,w2.w};
            #pragma unroll
            for (int c=0;c<12;c++)
                #pragma unroll
                for (int a=0;a<4;a++) acc[a][c] += av[a]*w[c];
        }
    }
    int b = win>>8, rem = win&255, wh = rem>>4, wwi = rem&15;
    #pragma unroll
    for (int a=0;a<4;a++){
        int t = rg + 16*a;
        int p = wh*8 + (t>>3), q = wwi*8 + (t&7);
        int hh = (p+SSH)&127, w2 = (q+SSH)&127;
        size_t pixb = (((size_t)b*128 + hh)*128 + w2)*192;
        #pragma unroll
        for (int c=0;c<12;c++){
            int ch = cg*12 + c;
            X1[pixb + ch] = acc[a][c] + proj_b[ch] + x[pixb + ch];
        }
    }
}

// ---------------- K5: LN2 + fc1 + exact GELU + fc2 + residual -> out ---------
__global__ __launch_bounds__(256) void k_mlp(const float* __restrict__ X1,
        const float* __restrict__ g2, const float* __restrict__ b2v,
        const float* __restrict__ fc1w, const float* __restrict__ fc1b,
        const float* __restrict__ fc2w, const float* __restrict__ fc2b,
        float* __restrict__ out){
    __shared__ __align__(16) float xln[64*196];
    __shared__ __align__(16) float Wbuf[12288];
    __shared__ float hch[64*68];
    int tid = threadIdx.x;
    size_t base = (size_t)blockIdx.x*64;
    {
        int tok = tid>>2, part = tid&3;
        const float* srcp = X1 + (base + tok)*192 + part*48;
        float v[48];
        #pragma unroll
        for (int i=0;i<12;i++){
            float4 t4 = *reinterpret_cast<const float4*>(srcp + i*4);
            v[i*4]=t4.x; v[i*4+1]=t4.y; v[i*4+2]=t4.z; v[i*4+3]=t4.w;
        }
        float s=0.f, ss=0.f;
        #pragma unroll
        for (int i=0;i<48;i++){ s+=v[i]; ss+=v[i]*v[i]; }
        s  += __shfl_xor(s,1);  s  += __shfl_xor(s,2);
        ss += __shfl_xor(ss,1); ss += __shfl_xor(ss,2);
        float mean = s*(1.f/192.f);
        float rstd = rsqrtf(ss*(1.f/192.f) - mean*mean + 1e-5f);
        #pragma unroll
        for (int i=0;i<48;i++){
            int ch = part*48 + i;
            xln[tok*196 + ch] = (v[i]-mean)*rstd*g2[ch] + b2v[ch];
        }
    }
    int rg = tid&15, cg = tid>>4;
    float acc[4][12];
    #pragma unroll
    for (int a=0;a<4;a++)
        #pragma unroll
        for (int c=0;c<12;c++) acc[a][c]=0.f;
    for (int cc=0; cc<12; cc++){
        __syncthreads();
        #pragma unroll
        for (int i=0;i<48;i++){
            int e = tid + i*256;          // 12288: W1 chunk [192][64]
            int ch = e>>6, j = e&63;
            Wbuf[e] = fc1w[ch*768 + cc*64 + j];
        }
        __syncthreads();
        float hv[4][4];
        #pragma unroll
        for (int a=0;a<4;a++)
            #pragma unroll
            for (int jb=0;jb<4;jb++) hv[a][jb] = fc1b[cc*64 + cg*4 + jb];
        for (int ch=0; ch<192; ch++){
            float av[4];
            #pragma unroll
            for (int a=0;a<4;a++) av[a] = xln[(rg+16*a)*196 + ch];
            float4 wq = *reinterpret_cast<const float4*>(&Wbuf[ch*64 + cg*4]);
            float wv4[4] = {wq.x, wq.y, wq.z, wq.w};
            #pragma unroll
            for (int jb=0;jb<4;jb++)
                #pragma unroll
                for (int a=0;a<4;a++) hv[a][jb] += av[a]*wv4[jb];
        }
        #pragma unroll
        for (int a=0;a<4;a++)
            #pragma unroll
            for (int jb=0;jb<4;jb++){
                float xv = hv[a][jb];
                hch[(rg+16*a)*68 + cg*4 + jb] =
                    0.5f*xv*(1.f + erff(xv*0.70710678118654752f));
            }
        __syncthreads();
        #pragma unroll
        for (int i=0;i<48;i++){
            int e = tid + i*256;          // W2 chunk [64][192]
            int j = e/192, ch = e - j*192;
            Wbuf[e] = fc2w[(cc*64 + j)*192 + ch];
        }
        __syncthreads();
        for (int j=0;j<64;j++){
            float hvv[4];
            #pragma unroll
            for (int a=0;a<4;a++) hvv[a] = hch[(rg+16*a)*68 + j];
            const float4* wp = reinterpret_cast<const float4*>(&Wbuf[j*192 + cg*12]);
            float4 w0 = wp[0], w1 = wp[1], w2 = wp[2];
            float w[12] = {w0.x,w0.y,w0.z,w0.w, w1.x,w1.y,w1.z,w1.w, w2.x,w2.y,w2.z,w2.w};
            #pragma unroll
            for (int c=0;c<12;c++)
                #pragma unroll
                for (int a=0;a<4;a++) acc[a][c] += hvv[a]*w[c];
        }
    }
    #pragma unroll
    for (int a=0;a<4;a++){
        size_t t = base + rg + 16*a;
        #pragma unroll
        for (int c=0;c<12;c++){
            int ch = cg*12 + c;
            out[t*192 + ch] = acc[a][c] + fc2b[ch] + X1[t*192 + ch];
        }
    }
}

extern "C" void kernel_launch(void* const* d_in, const int* in_sizes, int n_in,
                              void* d_out, int out_size, void* d_ws, size_t ws_size,
                              hipStream_t stream) {
    const float* x     = (const float*)d_in[0];
    const float* mask  = (const float*)d_in[1];
    const float* n1g   = (const float*)d_in[2];
    const float* n1b   = (const float*)d_in[3];
    const float* qkvw  = (const float*)d_in[4];
    const float* qkvb  = (const float*)d_in[5];
    const float* relt  = (const float*)d_in[6];
    const float* projw = (const float*)d_in[7];
    const float* projb = (const float*)d_in[8];
    const float* n2g   = (const float*)d_in[9];
    const float* n2b   = (const float*)d_in[10];
    const float* fc1w  = (const float*)d_in[11];
    const float* fc1b  = (const float*)d_in[12];
    const float* fc2w  = (const float*)d_in[13];
    const float* fc2b  = (const float*)d_in[14];
    float* out = (float*)d_out;

    bf16*  Sb = (bf16*)d_ws;                                   // 150,994,944 B
    float* X1 = (float*)((char*)d_ws + 150994944);             // 100,663,296 B

    k_qkv    <<<6144,  256, 0, stream>>>(x, n1g, n1b, qkvw, qkvb, Sb);
    k_spatial<<<2048,  256, 0, stream>>>(Sb, relt, mask, out);
    k_fattn  <<<12288, 256, 0, stream>>>(Sb, qkvb, out);
    k_proj   <<<2048,  256, 0, stream>>>(out, x, projw, projb, X1);
    k_mlp    <<<2048,  256, 0, stream>>>(X1, n2g, n2b, fc1w, fc1b, fc2w, fc2b, out);
}